// Round 13
// baseline (363.206 us; speedup 1.0000x reference)
//
#include <hip/hip_runtime.h>

// Problem constants (match reference file)
#define N_NODES  100000
#define N_EDGESC 1600000
#define EMB      128
#define N_GRAPHS 128
#define G_FEAT   32

// Bucketed CSR build parameters
#define BUKSH    9                      // bucket = tgt >> 9 (512 nodes/bucket)
#define NBUK     196                    // ceil(100000 / 512)
#define CHUNK_E  2048
#define NBLK_E   ((N_EDGESC + CHUNK_E - 1) / CHUNK_E)  // 782
#define PADSLK   4096                   // per-bucket pad slack (512 nodes x <=7)

typedef __attribute__((ext_vector_type(8))) short bf16x8;
typedef __attribute__((ext_vector_type(4))) float f32x4;

// Order-preserving float -> uint key for atomicMax-based float max.
__device__ __forceinline__ unsigned fkey(float f) {
  unsigned u = __float_as_uint(f);
  return (u & 0x80000000u) ? ~u : (u | 0x80000000u);
}
__device__ __forceinline__ float fkey_inv(unsigned k) {
  return (k & 0x80000000u) ? __uint_as_float(k & 0x7FFFFFFFu)
                           : __uint_as_float(~k);
}
__device__ __forceinline__ unsigned short f2bf(float f) {  // RNE
  unsigned u = __float_as_uint(f);
  u += 0x7fffu + ((u >> 16) & 1u);
  return (unsigned short)(u >> 16);
}

// ---------------- dtype conversion / weight packing ----------------

__global__ __launch_bounds__(256) void f2bf_kernel(const float* __restrict__ in,
                                                   unsigned short* __restrict__ out,
                                                   int n4) {
  int i = blockIdx.x * blockDim.x + threadIdx.x;
  if (i >= n4) return;
  float4 v = reinterpret_cast<const float4*>(in)[i];
  uint2 o;
  o.x = (unsigned)f2bf(v.x) | ((unsigned)f2bf(v.y) << 16);
  o.y = (unsigned)f2bf(v.z) | ((unsigned)f2bf(v.w) << 16);
  reinterpret_cast<uint2*>(out)[i] = o;
}

// Pack stacked weights [Wl(128x128); Wr(128x128)] -> MFMA B-fragment order:
// pack[((cb*8+kb)*64+lane)*8 + j] = W[k = kb*32+(lane>>4)*8+j][col = cb*16+(lane&15)]
__global__ __launch_bounds__(256) void pack_kernel(const float* __restrict__ Wl,
                                                   const float* __restrict__ Wr,
                                                   unsigned short* __restrict__ pack) {
  int id = blockIdx.x * blockDim.x + threadIdx.x;
  if (id >= 4096) return;
  int lane = id & 63;
  int kb = (id >> 6) & 7;
  int cb = id >> 9;
  int col = cb * 16 + (lane & 15);
  int k0 = kb * 32 + (lane >> 4) * 8;
  unsigned short v[8];
#pragma unroll
  for (int j = 0; j < 8; j++) {
    int k = k0 + j;
    float w = (k < 128) ? Wl[k * 128 + col] : Wr[(k - 128) * 128 + col];
    v[j] = f2bf(w);
  }
  uint4 o;
  o.x = (unsigned)v[0] | ((unsigned)v[1] << 16);
  o.y = (unsigned)v[2] | ((unsigned)v[3] << 16);
  o.z = (unsigned)v[4] | ((unsigned)v[5] << 16);
  o.w = (unsigned)v[6] | ((unsigned)v[7] << 16);
  *reinterpret_cast<uint4*>(pack + (size_t)id * 8) = o;
}

// ---------------- bucketed CSR build (write-locality-ordered) ----------------

// A: per-chunk LDS histogram over 196 coarse buckets.
__global__ __launch_bounds__(256) void bhistA_kernel(const int* __restrict__ tgti,
                                                     int* __restrict__ counts) {
  __shared__ int h[NBUK];
  for (int i = threadIdx.x; i < NBUK; i += 256) h[i] = 0;
  __syncthreads();
  int base = blockIdx.x * CHUNK_E;
  for (int i = threadIdx.x; i < CHUNK_E; i += 256) {
    int e = base + i;
    if (e < N_EDGESC) atomicAdd(&h[tgti[e] >> BUKSH], 1);
  }
  __syncthreads();
  for (int i = threadIdx.x; i < NBUK; i += 256)
    counts[blockIdx.x * NBUK + i] = h[i];
}

// B1: per-bucket totals. Block b tree-reduces its counts column.
__global__ __launch_bounds__(256) void bsumB1_kernel(const int* __restrict__ counts,
                                                     int* __restrict__ tot) {
  __shared__ int sh[256];
  int b = blockIdx.x;
  int t = threadIdx.x;
  int s = 0;
  for (int blk = t; blk < NBLK_E; blk += 256) s += counts[blk * NBUK + b];
  sh[t] = s;
  __syncthreads();
  for (int off = 128; off > 0; off >>= 1) {
    if (t < off) sh[t] += sh[t + off];
    __syncthreads();
  }
  if (t == 0) tot[b] = sh[0];
}

// B1b: exclusive scan of 196 totals -> bucketBase. One block (tiny).
__global__ __launch_bounds__(256) void bbaseB_kernel(const int* __restrict__ tot,
                                                     int* __restrict__ bucketBase) {
  __shared__ int sh[256];
  int t = threadIdx.x;
  int v = (t < NBUK) ? tot[t] : 0;
  sh[t] = v;
  __syncthreads();
  for (int off = 1; off < 256; off <<= 1) {
    int val = (t >= off) ? sh[t - off] : 0;
    __syncthreads();
    if (t >= off) sh[t] += val;
    __syncthreads();
  }
  if (t < NBUK) bucketBase[t] = sh[t] - v;
  if (t == 0) bucketBase[NBUK] = sh[NBUK - 1];  // == N_EDGESC
}

// B2: per-bucket exclusive scan over chunks -> stable offsets.
__global__ __launch_bounds__(256) void boffB2_kernel(const int* __restrict__ counts,
                                                     const int* __restrict__ bucketBase,
                                                     int* __restrict__ offsets) {
  __shared__ int sh[256];
  int b = blockIdx.x;
  int t = threadIdx.x;
  int v[4], s = 0;
#pragma unroll
  for (int i = 0; i < 4; i++) {
    int blk = t * 4 + i;
    v[i] = (blk < NBLK_E) ? counts[blk * NBUK + b] : 0;
    s += v[i];
  }
  sh[t] = s;
  __syncthreads();
  for (int off = 1; off < 256; off <<= 1) {
    int val = (t >= off) ? sh[t - off] : 0;
    __syncthreads();
    if (t >= off) sh[t] += val;
    __syncthreads();
  }
  int run = bucketBase[b] + sh[t] - s;
#pragma unroll
  for (int i = 0; i < 4; i++) {
    int blk = t * 4 + i;
    if (blk < NBLK_E) offsets[blk * NBUK + b] = run;
    run += v[i];
  }
}

// C: scatter packed (src | local_tgt<<17) into bucket-contiguous regions.
__global__ __launch_bounds__(256) void bscatC_kernel(const int* __restrict__ srci,
                                                     const int* __restrict__ tgti,
                                                     const int* __restrict__ offsets,
                                                     unsigned* __restrict__ bucketed) {
  __shared__ int cur[NBUK];
  for (int i = threadIdx.x; i < NBUK; i += 256)
    cur[i] = offsets[blockIdx.x * NBUK + i];
  __syncthreads();
  int base = blockIdx.x * CHUNK_E;
  for (int i = threadIdx.x; i < CHUNK_E; i += 256) {
    int e = base + i;
    if (e < N_EDGESC) {
      int t = tgti[e];
      int bk = t >> BUKSH;
      int pos = atomicAdd(&cur[bk], 1);
      bucketed[pos] = (unsigned)srci[e] |
                      ((unsigned)(t & ((1 << BUKSH) - 1)) << 17);
    }
  }
}

// D: one block per bucket. Builds PADDED CSR: each node's edge list padded to
// a multiple of 8 with N_NODES (zero-row) entries -> aggb needs no predication.
// rowstart[n] = padded start; degv[n] = true degree (for mean scale).
__global__ __launch_bounds__(256) void bcsrD_kernel(const unsigned* __restrict__ bucketed,
                                                    const int* __restrict__ bucketBase,
                                                    int* __restrict__ rowstart,
                                                    int* __restrict__ degv,
                                                    int* __restrict__ ebuf) {
  __shared__ int sdeg[512];
  __shared__ int spre[512];
  __shared__ int scur[512];
  __shared__ int sh2[256];
  int bk = blockIdx.x;
  int node0 = bk << BUKSH;
  int nn = min(512, N_NODES - node0);
  int beg = bucketBase[bk], end = bucketBase[bk + 1];
  int padBase = beg + bk * PADSLK;
  for (int i = threadIdx.x; i < 512; i += 256) sdeg[i] = 0;
  __syncthreads();
  for (int j = beg + threadIdx.x; j < end; j += 256)
    atomicAdd(&sdeg[bucketed[j] >> 17], 1);
  __syncthreads();
  // exclusive scan over PADDED degrees (2 nodes per thread)
  int t = threadIdx.x;
  int d0 = sdeg[2 * t], d1 = sdeg[2 * t + 1];
  int p0 = (d0 + 7) & ~7, p1 = (d1 + 7) & ~7;
  sh2[t] = p0 + p1;
  __syncthreads();
  for (int off = 1; off < 256; off <<= 1) {
    int val = (t >= off) ? sh2[t - off] : 0;
    __syncthreads();
    if (t >= off) sh2[t] += val;
    __syncthreads();
  }
  int ex = sh2[t] - p0 - p1;
  spre[2 * t] = ex;
  spre[2 * t + 1] = ex + p0;
  __syncthreads();
  for (int i = t; i < nn; i += 256) {
    rowstart[node0 + i] = padBase + spre[i];
    degv[node0 + i] = sdeg[i];
  }
  for (int i = t; i < 512; i += 256) scur[i] = spre[i];
  __syncthreads();
  for (int j = beg + t; j < end; j += 256) {
    unsigned p = bucketed[j];
    int ln = p >> 17;
    int pos = atomicAdd(&scur[ln], 1);
    ebuf[padBase + pos] = (int)(p & 0x1FFFFu);
  }
  // pad fill (slots disjoint from real fills; sdeg/spre stable)
  for (int i = t; i < nn; i += 256) {
    int d = sdeg[i];
    int dp = (d + 7) & ~7;
    for (int p = d; p < dp; p++) ebuf[padBase + spre[i] + p] = N_NODES;
  }
}

// ---------------- mean aggregation (bf16 gather, no atomics) ----------------
// 2 nodes per wave: half-wave of 32 lanes per node, lane owns 4 dims (8 B).
// Edge lists are padded to x8 with zero-row indices -> NO predication at all.
// float2 packed accumulation (v_pk_add_f32-friendly).
__global__ __launch_bounds__(256) void aggb_kernel(const unsigned short* __restrict__ featB,
                                                   const int* __restrict__ ebuf,
                                                   const int* __restrict__ rowstart,
                                                   const int* __restrict__ degv,
                                                   unsigned short* __restrict__ aggB) {
  int wid = (blockIdx.x * 256 + threadIdx.x) >> 6;  // global wave id
  int lane = threadIdx.x & 63;
  int node = wid * 2 + (lane >> 5);
  if (node >= N_NODES) return;
  int l = lane & 31;
  int beg = rowstart[node];
  int d = degv[node];
  int endp = beg + ((d + 7) & ~7);
  const unsigned short* fb = featB + l * 4;  // lane's 4-dim slice (8 B)
  float2 A0 = {0.0f, 0.0f}, A1 = {0.0f, 0.0f};
  for (int j = beg; j < endp; j += 8) {
    uint2 u[8];
#pragma unroll
    for (int i = 0; i < 8; i++) {
      int s = ebuf[j + i];  // always valid: real src or N_NODES (zero row)
      u[i] = *reinterpret_cast<const uint2*>(fb + (size_t)s * EMB);
    }
#pragma unroll
    for (int i = 0; i < 8; i++) {
      A0.x += __uint_as_float(u[i].x << 16);
      A0.y += __uint_as_float(u[i].x & 0xffff0000u);
      A1.x += __uint_as_float(u[i].y << 16);
      A1.y += __uint_as_float(u[i].y & 0xffff0000u);
    }
  }
  float inv = 1.0f / fmaxf((float)d, 1.0f);
  uint2 o;
  o.x = (unsigned)f2bf(A0.x * inv) | ((unsigned)f2bf(A0.y * inv) << 16);
  o.y = (unsigned)f2bf(A1.x * inv) | ((unsigned)f2bf(A1.y * inv) << 16);
  *reinterpret_cast<uint2*>(aggB + (size_t)node * EMB + l * 4) = o;
}

// ---------------- node GEMM via MFMA: out = [relu]([agg|x] @ [Wl;Wr] + bl) ----
// 64 nodes/block, 4 waves x 16 rows. A-frags direct from global; B from pack.
// POOL: stage to LDS, segment-reduce per column (batch_idx sorted), few atomics.
template <bool RELU, bool POOL>
__global__ __launch_bounds__(256) void nodeMM_kernel(
    const unsigned short* __restrict__ aggB, const unsigned short* __restrict__ xB,
    const unsigned short* __restrict__ pack, const float* __restrict__ bl,
    const int* __restrict__ batch, unsigned short* __restrict__ hout,
    float* __restrict__ gsum, unsigned* __restrict__ gmax) {
  int w = threadIdx.x >> 6;
  int lane = threadIdx.x & 63;
  int wbase = blockIdx.x * 64 + w * 16;
  bool active = (wbase < N_NODES);  // N_NODES % 16 == 0 -> whole wave valid

  f32x4 acc[8];
  if (active) {
    bf16x8 afrag[8];
    int row = wbase + (lane & 15);
    int koff = (lane >> 4) * 8;
    const unsigned short* ap = aggB + (size_t)row * EMB + koff;
    const unsigned short* xp = xB + (size_t)row * EMB + koff;
#pragma unroll
    for (int kb = 0; kb < 4; kb++) afrag[kb] = *reinterpret_cast<const bf16x8*>(ap + kb * 32);
#pragma unroll
    for (int kb = 0; kb < 4; kb++) afrag[4 + kb] = *reinterpret_cast<const bf16x8*>(xp + kb * 32);
#pragma unroll
    for (int cb = 0; cb < 8; cb++) {
      f32x4 a = {0.0f, 0.0f, 0.0f, 0.0f};
#pragma unroll
      for (int kb = 0; kb < 8; kb++) {
        bf16x8 b = *reinterpret_cast<const bf16x8*>(pack + ((size_t)(cb * 8 + kb) * 64 + lane) * 8);
        a = __builtin_amdgcn_mfma_f32_16x16x32_bf16(afrag[kb], b, a, 0, 0, 0);
      }
      acc[cb] = a;
    }
  }

  if constexpr (!POOL) {
    if (active) {
#pragma unroll
      for (int cb = 0; cb < 8; cb++) {
        int col = cb * 16 + (lane & 15);
        float bias = bl[col];
#pragma unroll
        for (int r = 0; r < 4; r++) {
          float v = acc[cb][r] + bias;
          if (RELU) v = fmaxf(v, 0.0f);
          int rowl = (lane >> 4) * 4 + r;  // C/D: col=lane&15, row=(lane>>4)*4+r
          hout[(size_t)(wbase + rowl) * EMB + col] = f2bf(v);
        }
      }
    }
  } else {
    __shared__ float sh[64][130];
    __shared__ int sBatch[64];
    if (threadIdx.x < 64) {
      int node = blockIdx.x * 64 + threadIdx.x;
      sBatch[threadIdx.x] = batch[node < N_NODES ? node : (N_NODES - 1)];
    }
    if (active) {
#pragma unroll
      for (int cb = 0; cb < 8; cb++) {
        int col = cb * 16 + (lane & 15);
        float bias = bl[col];
#pragma unroll
        for (int r = 0; r < 4; r++) {
          float v = acc[cb][r] + bias;
          if (RELU) v = fmaxf(v, 0.0f);
          sh[w * 16 + (lane >> 4) * 4 + r][col] = v;
        }
      }
    }
    __syncthreads();
    // Segment reduction: thread t owns column (t&127), rows half*32..+31.
    int col = threadIdx.x & 127;
    int half = threadIdx.x >> 7;
    int nbase = blockIdx.x * 64 + half * 32;
    float rs = 0.0f, rm = -INFINITY;
    int cur = -1;
    for (int r = 0; r < 32; r++) {
      if (nbase + r >= N_NODES) break;
      int b = sBatch[half * 32 + r];
      float v = sh[half * 32 + r][col];
      if (b != cur) {
        if (cur >= 0) {
          atomicAdd(&gsum[cur * EMB + col], rs);
          atomicMax(&gmax[cur * EMB + col], fkey(rm));
        }
        cur = b; rs = 0.0f; rm = -INFINITY;
      }
      rs += v;
      rm = fmaxf(rm, v);
    }
    if (cur >= 0) {
      atomicAdd(&gsum[cur * EMB + col], rs);
      atomicMax(&gmax[cur * EMB + col], fkey(rm));
    }
  }
}

// batch_idx is SORTED -> per-graph counts via binary search, no atomics.
__global__ __launch_bounds__(128) void gcnt_kernel(const int* __restrict__ batch,
                                                   float* __restrict__ gcnt) {
  __shared__ int lb[129];
  int g = threadIdx.x;
  int lo = 0, hi = N_NODES;
  while (lo < hi) {
    int mid = (lo + hi) >> 1;
    if (batch[mid] < g) lo = mid + 1; else hi = mid;
  }
  lb[g] = lo;
  if (g == 0) lb[128] = N_NODES;
  __syncthreads();
  gcnt[g] = (float)(lb[g + 1] - lb[g]);
}

// One block per graph, 128 threads = one per embedding dim.
__global__ __launch_bounds__(128) void readout_kernel(
    const float* __restrict__ gsum, const unsigned* __restrict__ gmax,
    const float* __restrict__ gcnt, const float* __restrict__ gfeat,
    const float* __restrict__ Wg, const float* __restrict__ bg,
    const float* __restrict__ Wo, const float* __restrict__ bo,
    float* __restrict__ out) {
  int g = blockIdx.x, d = threadIdx.x;
  float mean = gsum[g * EMB + d] / fmaxf(gcnt[g], 1.0f);
  float mx = fkey_inv(gmax[g * EMB + d]);
  float gfe = bg[d];
#pragma unroll
  for (int k = 0; k < G_FEAT; k++) gfe += gfeat[g * G_FEAT + k] * Wg[k * EMB + d];
  float l0 = mean * Wo[d * 2 + 0] + mx * Wo[(EMB + d) * 2 + 0] +
             gfe * Wo[(2 * EMB + d) * 2 + 0];
  float l1 = mean * Wo[d * 2 + 1] + mx * Wo[(EMB + d) * 2 + 1] +
             gfe * Wo[(2 * EMB + d) * 2 + 1];
  __shared__ float s0[128], s1[128];
  s0[d] = l0; s1[d] = l1;
  __syncthreads();
  for (int off = 64; off > 0; off >>= 1) {
    if (d < off) { s0[d] += s0[d + off]; s1[d] += s1[d + off]; }
    __syncthreads();
  }
  if (d == 0) {
    float a = s0[0] + bo[0];
    float b = s1[0] + bo[1];
    float m = fmaxf(a, b);
    float lse = m + logf(expf(a - m) + expf(b - m));
    out[g * 2 + 0] = a - lse;
    out[g * 2 + 1] = b - lse;
  }
}

extern "C" void kernel_launch(void* const* d_in, const int* in_sizes, int n_in,
                              void* d_out, int out_size, void* d_ws,
                              size_t ws_size, hipStream_t stream) {
  const float* x     = (const float*)d_in[0];
  const int*   edges = (const int*)d_in[1];
  const int*   batch = (const int*)d_in[2];
  const float* gfeat = (const float*)d_in[3];
  const float* W_l0  = (const float*)d_in[4];
  const float* b_l0  = (const float*)d_in[5];
  const float* W_r0  = (const float*)d_in[6];
  const float* W_l1  = (const float*)d_in[7];
  const float* b_l1  = (const float*)d_in[8];
  const float* W_r1  = (const float*)d_in[9];
  const float* W_g   = (const float*)d_in[10];
  const float* b_g   = (const float*)d_in[11];
  const float* W_o   = (const float*)d_in[12];
  const float* b_o   = (const float*)d_in[13];
  const int* srci = edges;
  const int* tgti = edges + N_EDGESC;

  // Workspace layout. Zeroed region first: [gsum | gmax | gcnt]
  char* ws = (char*)d_ws;
  float*    gsum     = (float*)ws;                          // 128*128
  unsigned* gmax     = (unsigned*)(gsum + N_GRAPHS * EMB);  // 128*128
  float*    gcnt     = (float*)(gmax + N_GRAPHS * EMB);     // 128
  // xB and hB carry an extra ZERO row at index N_NODES (gather pad target).
  unsigned short* xB   = (unsigned short*)(gcnt + N_GRAPHS);       // (N+1)*128 bf16
  unsigned short* aggB = xB + (size_t)(N_NODES + 1) * EMB;         // N*128 bf16
  unsigned short* hB   = aggB + (size_t)N_NODES * EMB;             // (N+1)*128 bf16
  unsigned short* pack0 = hB + (size_t)(N_NODES + 1) * EMB;        // 32768 bf16
  unsigned short* pack1 = pack0 + 8 * 8 * 64 * 8;                  // 32768 bf16
  int*      ebuf     = (int*)(pack1 + 8 * 8 * 64 * 8);      // E + NBUK*PADSLK
  int*      rowstart = ebuf + N_EDGESC + NBUK * PADSLK;     // N+1
  int*      degv     = rowstart + N_NODES + 1;              // N
  int*      bucketBase = degv + N_NODES;                    // NBUK+1
  int*      tot      = bucketBase + NBUK + 4;               // NBUK (pad)
  // CSR-build scratch aliased into regions written only AFTER the build:
  int*      counts   = (int*)aggB;                          // NBLK_E*NBUK ints (<1.3MB)
  int*      offsets  = counts + NBLK_E * NBUK;              // NBLK_E*NBUK ints
  unsigned* bucketed = (unsigned*)hB;                       // E uints (6.4MB < 25.6MB)

  // Zero gsum/gmax/gcnt (131.5 KB) + the two 256 B zero rows.
  size_t zbytes = (size_t)((char*)xB - ws);
  hipMemsetAsync(d_ws, 0, zbytes, stream);
  hipMemsetAsync(xB + (size_t)N_NODES * EMB, 0, EMB * sizeof(unsigned short), stream);
  hipMemsetAsync(hB + (size_t)N_NODES * EMB, 0, EMB * sizeof(unsigned short), stream);

  dim3 b256(256);

  // Conversions / packing (small)
  f2bf_kernel<<<(N_NODES * EMB / 4 + 255) / 256, b256, 0, stream>>>(x, xB,
                                                                    N_NODES * EMB / 4);
  pack_kernel<<<16, b256, 0, stream>>>(W_l0, W_r0, pack0);
  pack_kernel<<<16, b256, 0, stream>>>(W_l1, W_r1, pack1);

  // Bucketed CSR build (shared by both layers)
  bhistA_kernel<<<NBLK_E, b256, 0, stream>>>(tgti, counts);
  bsumB1_kernel<<<NBUK, b256, 0, stream>>>(counts, tot);
  bbaseB_kernel<<<1, b256, 0, stream>>>(tot, bucketBase);
  boffB2_kernel<<<NBUK, b256, 0, stream>>>(counts, bucketBase, offsets);
  bscatC_kernel<<<NBLK_E, b256, 0, stream>>>(srci, tgti, offsets, bucketed);
  bcsrD_kernel<<<NBUK, b256, 0, stream>>>(bucketed, bucketBase, rowstart, degv, ebuf);
  gcnt_kernel<<<1, 128, 0, stream>>>(batch, gcnt);

  int ngrid = (N_NODES + 63) / 64;   // 1563
  int agrid = (N_NODES + 7) / 8;     // 12500 (2 nodes/wave, 4 waves/block)

  // Layer 0
  aggb_kernel<<<agrid, b256, 0, stream>>>(xB, ebuf, rowstart, degv, aggB);
  nodeMM_kernel<true, false><<<ngrid, b256, 0, stream>>>(
      aggB, xB, pack0, b_l0, nullptr, hB, nullptr, nullptr);

  // Layer 1
  aggb_kernel<<<agrid, b256, 0, stream>>>(hB, ebuf, rowstart, degv, aggB);
  nodeMM_kernel<false, true><<<ngrid, b256, 0, stream>>>(
      aggB, hB, pack1, b_l1, batch, nullptr, gsum, gmax);

  // Readout
  readout_kernel<<<N_GRAPHS, 128, 0, stream>>>(gsum, gmax, gcnt, gfeat, W_g,
                                               b_g, W_o, b_o, (float*)d_out);
}